// Round 13
// baseline (23.127 us; speedup 1.0000x reference)
//
#include <hip/hip_runtime.h>

#define NPART   2048
#define NCOMP   8192
#define NBATCH  8
#define THRESH  0.05f
#define FLTMAX  3.4028235e38f

#define SEGS    32                        // partial segments per block
#define SEGLEN  (NPART / SEGS)            // 64 partials per segment
#define PGRPS   8                         // point groups per block
#define PPT     4                         // points per thread
#define PTSBLK  (PGRPS * PPT)             // 32 completed points per block
#define BLKSPB  (NCOMP / PTSBLK)          // 256 blocks per batch
#define GRID    (NBATCH * BLKSPB)         // 2048 blocks x 256 thr
                                          //  = 8 blocks/CU = 8 waves/SIMD

__global__ __launch_bounds__(256, 8) void pml_main(
    const float* __restrict__ completed,
    const float* __restrict__ partial,
    float2* __restrict__ slots_out)
{
    const int tid   = threadIdx.x;
    const int pg    = tid & (PGRPS - 1);     // 0..7  point group
    const int sg    = tid >> 3;              // 0..31 partial segment
    const int batch = blockIdx.x >> 8;
    const int blkb  = blockIdx.x & (BLKSPB - 1);

    __shared__ float smin[PTSBLK][SEGS + 1]; // 4.2 KB, pitch 33
    __shared__ float rs0;                    // unused pad avoidance
    (void)rs0;

    // ---- this thread's 4 completed points ----
    const float* cb = completed +
        ((size_t)batch * NCOMP + (size_t)blkb * PTSBLK + (size_t)pg * PPT) * 3;
    float nx[PPT], ny[PPT], nz[PPT];
    #pragma unroll
    for (int k = 0; k < PPT; ++k) {
        float x = cb[3 * k + 0];
        float y = cb[3 * k + 1];
        float z = cb[3 * k + 2];
        nx[k] = -2.0f * x;
        ny[k] = -2.0f * y;
        nz[k] = -2.0f * z;
    }

    // ---- scan this thread's 64-partial segment from global/L1 ----
    // 8 distinct address streams per wave (lanes sharing sg broadcast).
    // t = |p|^2 - 2 c.p ; |p|^2 recomputed in-register (amortized over 4 pts).
    const float4* pv = reinterpret_cast<const float4*>(
        partial + ((size_t)batch * NPART + (size_t)sg * SEGLEN) * 3);

    float acc[PPT];
    #pragma unroll
    for (int k = 0; k < PPT; ++k) acc[k] = FLTMAX;

    for (int i = 0; i < SEGLEN / 4; ++i) {
        float4 r0 = pv[3 * i + 0];           // p0x p0y p0z p1x
        float4 r1 = pv[3 * i + 1];           // p1y p1z p2x p2y
        float4 r2 = pv[3 * i + 2];           // p2z p3x p3y p3z
        float p0w = fmaf(r0.x, r0.x, fmaf(r0.y, r0.y, r0.z * r0.z));
        float p1w = fmaf(r0.w, r0.w, fmaf(r1.x, r1.x, r1.y * r1.y));
        float p2w = fmaf(r1.z, r1.z, fmaf(r1.w, r1.w, r2.x * r2.x));
        float p3w = fmaf(r2.y, r2.y, fmaf(r2.z, r2.z, r2.w * r2.w));
        #pragma unroll
        for (int k = 0; k < PPT; ++k) {
            float t0 = fmaf(r0.x, nx[k], fmaf(r0.y, ny[k], fmaf(r0.z, nz[k], p0w)));
            float t1 = fmaf(r0.w, nx[k], fmaf(r1.x, ny[k], fmaf(r1.y, nz[k], p1w)));
            float t2 = fmaf(r1.z, nx[k], fmaf(r1.w, ny[k], fmaf(r2.x, nz[k], p2w)));
            float t3 = fmaf(r2.y, nx[k], fmaf(r2.z, ny[k], fmaf(r2.w, nz[k], p3w)));
            // fuses to 2x v_min3_f32; 4 independent chains across k
            acc[k] = fminf(fminf(fminf(fminf(acc[k], t0), t1), t2), t3);
        }
    }

    #pragma unroll
    for (int k = 0; k < PPT; ++k)
        smin[pg * PPT + k][sg] = acc[k];     // one-time write
    __syncthreads();

    // ---- combine 32 segment-minima per point, +c2, mask, reduce ----
    float        v = 0.0f;
    unsigned int c = 0u;
    if (tid < PTSBLK) {
        // lane l reads words l*33+g: bank (l+g)%32 -> conflict-free
        float t = smin[tid][0];
        #pragma unroll
        for (int g = 1; g < SEGS; ++g) t = fminf(t, smin[tid][g]);
        const float* cp = completed +
            ((size_t)batch * NCOMP + (size_t)blkb * PTSBLK + tid) * 3;
        float x = cp[0], y = cp[1], z = cp[2];
        float c2 = fmaf(x, x, fmaf(y, y, z * z));
        float m = fmaxf(c2 + t, 0.0f);
        if (m < THRESH) { v = m; c = 1u; }
    }
    if (tid < 64) {                          // wave 0 reduces (lanes >=32 carry 0)
        #pragma unroll
        for (int off = 32; off >= 1; off >>= 1) {
            v += __shfl_down(v, off, 64);
            c += __shfl_down(c, off, 64);
        }
        if (tid == 0)
            slots_out[blockIdx.x] = make_float2(v, (float)c);
    }
}

__global__ __launch_bounds__(256) void pml_fin(
    const float2* __restrict__ slots_in,
    float* __restrict__ out)
{
    const int tid = threadIdx.x;
    float s = 0.0f, c = 0.0f;
    #pragma unroll
    for (int j = 0; j < GRID / 256; ++j) {   // 8 coalesced strides
        float2 sl = slots_in[tid + j * 256];
        s += sl.x;
        c += sl.y;
    }
    #pragma unroll
    for (int off = 32; off >= 1; off >>= 1) {
        s += __shfl_down(s, off, 64);
        c += __shfl_down(c, off, 64);
    }
    __shared__ float ss[4], sc[4];
    if ((tid & 63) == 0) { ss[tid >> 6] = s; sc[tid >> 6] = c; }
    __syncthreads();
    if (tid == 0) {
        float s2 = ss[0] + ss[1] + ss[2] + ss[3];
        float c2 = sc[0] + sc[1] + sc[2] + sc[3];
        *out = (c2 > 0.0f) ? (s2 / (c2 + 1e-6f)) : 0.0f;   // WEIGHT = 1.0
    }
}

extern "C" void kernel_launch(void* const* d_in, const int* in_sizes, int n_in,
                              void* d_out, int out_size, void* d_ws, size_t ws_size,
                              hipStream_t stream) {
    const float* completed = (const float*)d_in[0];  // (8, 8192, 3) f32
    const float* partial   = (const float*)d_in[1];  // (8, 2048, 3) f32
    float* out = (float*)d_out;
    float2* slots = (float2*)d_ws;                   // 2048 slots, all written
                                                     // before fin reads them:
                                                     // no memset node needed

    pml_main<<<dim3(GRID), dim3(256), 0, stream>>>(completed, partial, slots);
    pml_fin<<<dim3(1), dim3(256), 0, stream>>>(slots, out);
}

// Round 14
// 17.844 us; speedup vs baseline: 1.2960x; 1.2960x over previous
//
#include <hip/hip_runtime.h>

typedef __attribute__((ext_vector_type(8))) short bf16x8;
typedef __attribute__((ext_vector_type(4))) float f32x4;

#define NPART   2048
#define NCOMP   8192
#define NBATCH  8
#define THRESH  0.05f
#define FLTMAX  3.4028235e38f

#define WAVES   16
#define PTSBLK  256
#define PTILES  (PTSBLK / 16)              // 16 point-tiles (B) per block
#define ACHUNKS 8                          // A-chunks per wave = 8 x 16 = 128 partials
#define BLKSPB  (NCOMP / PTSBLK)           // 32 blocks per batch
#define GRID    (NBATCH * BLKSPB)          // 256 blocks

__device__ __forceinline__ unsigned int bf16rne(float x) {
    unsigned int b = __float_as_uint(x);
    return (b + 0x7FFFu + ((b >> 16) & 1u)) >> 16;
}
__device__ __forceinline__ float bf16tof(unsigned int h) {
    return __uint_as_float(h << 16);
}

union frag_cast { uint4 u; bf16x8 v; };

// Split-precision bf16 MFMA encoding (verified absmax=0 in R11/R12), with
// OPERANDS SWAPPED so D-rows = partials and the min folds in-register:
//   A row (partial) k0..15 = [qhx,qhy,qhz, qhx,qhy,qhz, qlx,qly, qlz, p2h, p2l, 0...]
//   B col (point)   k0..15 = [chx,chy,chz, clx,cly,clz, chx,chy, chz, 1, 1, 0...]
//   dot = qh.(ch+cl) + ql.ch + p2 ~= -2 c.p + |p|^2
// Layouts (R11-verified for 16x16x32): A row=l&15 k-grp=l>>4; B col=l&15; 
// D col=l&15, row=4*(l>>4)+reg.
__global__ __launch_bounds__(1024, 4) void pml_main(
    const float* __restrict__ completed,
    const float* __restrict__ partial,
    float2* __restrict__ slots_out)
{
    const int tid  = threadIdx.x;
    const int lane = tid & 63;
    const int wave = tid >> 6;            // 0..15, owns 128 partials
    const int g    = lane >> 4;           // k-group / D row-group
    const int lr   = lane & 15;           // B col (point) / A row (partial)
    const int batch = blockIdx.x >> 5;
    const int blkb  = blockIdx.x & (BLKSPB - 1);

    __shared__ uint4 sB[PTILES][2][16];         // 8 KB B-frags (points)
    __shared__ float smin[PTSBLK][WAVES + 1];   // 17 KB, pitch 17
    __shared__ float        rs[4];
    __shared__ unsigned int rc[4];

    const size_t cbase = ((size_t)batch * NCOMP + (size_t)blkb * PTSBLK) * 3;

    // ---- encode B-frags (block's 256 points) into LDS: tid<512 ----
    if (tid < 512) {
        const int tt = tid >> 5;              // tile
        const int sl = tid & 31;
        const int bg = sl >> 4;               // k-group 0/1
        const int pt = sl & 15;               // point in tile
        const float* p = completed + cbase + 3 * (tt * 16 + pt);
        float x = p[0], y = p[1], z = p[2];
        uint4 o;
        if (bg == 0) {
            unsigned int hx = bf16rne(x), hy = bf16rne(y), hz = bf16rne(z);
            unsigned int lx = bf16rne(x - bf16tof(hx));
            unsigned int ly = bf16rne(y - bf16tof(hy));
            unsigned int lz = bf16rne(z - bf16tof(hz));
            o.x = hx | (hy << 16);
            o.y = hz | (lx << 16);
            o.z = ly | (lz << 16);
            o.w = hx | (hy << 16);
        } else {                              // k8..15 = [chz, 1, 1, 0...]
            unsigned int hz = bf16rne(z);
            o.x = hz | (0x3F80u << 16);
            o.y = 0x3F80u;
            o.z = 0u;
            o.w = 0u;
        }
        sB[tt][bg][pt] = o;
    }

    // ---- encode this wave's 8 A-chunks (128 partials) in-register ----
    bf16x8 pa[ACHUNKS];
    {
        const size_t pbase = (size_t)batch * NPART + (size_t)wave * 128;
        #pragma unroll
        for (int i = 0; i < ACHUNKS; ++i) {
            const float* pp = partial + 3 * (pbase + i * 16 + lr);
            float px = pp[0], py = pp[1], pz = pp[2];
            frag_cast fc; fc.u = make_uint4(0u, 0u, 0u, 0u);
            if (g == 0) {
                float qx = -2.0f * px, qy = -2.0f * py, qz = -2.0f * pz;
                unsigned int qhx = bf16rne(qx), qhy = bf16rne(qy), qhz = bf16rne(qz);
                unsigned int qlx = bf16rne(qx - bf16tof(qhx));
                unsigned int qly = bf16rne(qy - bf16tof(qhy));
                fc.u.x = qhx | (qhy << 16);
                fc.u.y = qhz | (qhx << 16);
                fc.u.z = qhy | (qhz << 16);
                fc.u.w = qlx | (qly << 16);
            } else if (g == 1) {              // k8..15 = [qlz, p2h, p2l, 0...]
                float qz = -2.0f * pz;
                float p2 = fmaf(px, px, fmaf(py, py, pz * pz));
                unsigned int qhz = bf16rne(qz);
                unsigned int qlz = bf16rne(qz - bf16tof(qhz));
                unsigned int p2h = bf16rne(p2);
                unsigned int p2l = bf16rne(p2 - bf16tof(p2h));
                fc.u.x = qlz | (p2h << 16);
                fc.u.y = p2l;
            }
            pa[i] = fc.v;
        }
    }

    __syncthreads();   // sB visible

    const f32x4 zero4 = {0.0f, 0.0f, 0.0f, 0.0f};

    // ---- sweep 16 point-tiles: min over partials folds in the accumulator ----
    for (int tile = 0; tile < PTILES; ++tile) {
        bf16x8 bf = {};
        if (g < 2) {
            frag_cast fc; fc.u = sB[tile][g][lr];
            bf = fc.v;
        }
        f32x4 acc = {FLTMAX, FLTMAX, FLTMAX, FLTMAX};
        #pragma unroll
        for (int i = 0; i < ACHUNKS; ++i) {
            f32x4 d = __builtin_amdgcn_mfma_f32_16x16x32_bf16(pa[i], bf, zero4, 0, 0, 0);
            acc[0] = fminf(acc[0], d[0]);
            acc[1] = fminf(acc[1], d[1]);
            acc[2] = fminf(acc[2], d[2]);
            acc[3] = fminf(acc[3], d[3]);
        }
        // in-lane rows, then fold lane-groups: 2 shuffles, no DPP chains
        float m = fminf(fminf(acc[0], acc[1]), fminf(acc[2], acc[3]));
        m = fminf(m, __shfl_xor(m, 16, 64));
        m = fminf(m, __shfl_xor(m, 32, 64));
        if (g == 0)
            smin[tile * 16 + lr][wave] = m;   // banks 17*(t*16+lr): distinct
    }
    __syncthreads();

    // ---- combine 16 wave-minima per point, +c2 (exact f32), mask, reduce ----
    float        v = 0.0f;
    unsigned int c = 0u;
    if (tid < PTSBLK) {
        float t = smin[tid][0];
        #pragma unroll
        for (int g2 = 1; g2 < WAVES; ++g2) t = fminf(t, smin[tid][g2]);
        const float* cp = completed + cbase + 3 * tid;
        float x = cp[0], y = cp[1], z = cp[2];
        float c2 = fmaf(x, x, fmaf(y, y, z * z));
        float m = fmaxf(c2 + t, 0.0f);
        if (m < THRESH) { v = m; c = 1u; }
        #pragma unroll
        for (int off = 32; off >= 1; off >>= 1) {
            v += __shfl_down(v, off, 64);
            c += __shfl_down(c, off, 64);
        }
        if ((tid & 63) == 0) { rs[tid >> 6] = v; rc[tid >> 6] = c; }
    }
    __syncthreads();
    if (tid == 0) {
        float        bs = 0.0f;
        unsigned int bc = 0u;
        #pragma unroll
        for (int w = 0; w < PTSBLK / 64; ++w) { bs += rs[w]; bc += rc[w]; }
        slots_out[blockIdx.x] = make_float2(bs, (float)bc);
    }
}

__global__ __launch_bounds__(256) void pml_fin(
    const float2* __restrict__ slots_in,
    float* __restrict__ out)
{
    const int tid = threadIdx.x;
    float2 sl = slots_in[tid];               // GRID == 256 == blockDim
    float s = sl.x, c = sl.y;
    #pragma unroll
    for (int off = 32; off >= 1; off >>= 1) {
        s += __shfl_down(s, off, 64);
        c += __shfl_down(c, off, 64);
    }
    __shared__ float ss[4], sc[4];
    if ((tid & 63) == 0) { ss[tid >> 6] = s; sc[tid >> 6] = c; }
    __syncthreads();
    if (tid == 0) {
        float s2 = ss[0] + ss[1] + ss[2] + ss[3];
        float c2 = sc[0] + sc[1] + sc[2] + sc[3];
        *out = (c2 > 0.0f) ? (s2 / (c2 + 1e-6f)) : 0.0f;   // WEIGHT = 1.0
    }
}

extern "C" void kernel_launch(void* const* d_in, const int* in_sizes, int n_in,
                              void* d_out, int out_size, void* d_ws, size_t ws_size,
                              hipStream_t stream) {
    const float* completed = (const float*)d_in[0];  // (8, 8192, 3) f32
    const float* partial   = (const float*)d_in[1];  // (8, 2048, 3) f32
    float* out = (float*)d_out;
    float2* slots = (float2*)d_ws;                   // 256 slots, all written
                                                     // before fin reads them:
                                                     // no memset node needed

    pml_main<<<dim3(GRID), dim3(1024), 0, stream>>>(completed, partial, slots);
    pml_fin<<<dim3(1), dim3(256), 0, stream>>>(slots, out);
}

// Round 15
// 14.252 us; speedup vs baseline: 1.6227x; 1.2520x over previous
//
#include <hip/hip_runtime.h>

typedef __attribute__((ext_vector_type(8)))  short bf16x8;
typedef __attribute__((ext_vector_type(16))) float f32x16;

#define NPART   2048
#define NCOMP   8192
#define NBATCH  8
#define THRESH  0.05f
#define FLTMAX  3.4028235e38f

#define WAVES   16
#define PTSBLK  256
#define PTILES  (PTSBLK / 32)              // 8 point-tiles (B cols) per block
#define ACHUNKS 4                          // A-chunks per wave = 4 x 32 = 128 partials
#define BLKSPB  (NCOMP / PTSBLK)           // 32 blocks per batch
#define GRID    (NBATCH * BLKSPB)          // 256 blocks

__device__ __forceinline__ unsigned int bf16rne(float x) {
    unsigned int b = __float_as_uint(x);
    return (b + 0x7FFFu + ((b >> 16) & 1u)) >> 16;
}
__device__ __forceinline__ float bf16tof(unsigned int h) {
    return __uint_as_float(h << 16);
}

union frag_cast { uint4 u; bf16x8 v; };

// Split-precision bf16 encoding (verified absmax=0 in R11/R12/R14), now on
// 32x32x16 (K=16 holds the K=11 contraction; 2.4x pair-throughput of 16x16x32):
//   A row (partial) k0..15 = [qhx,qhy,qhz, qhx,qhy,qhz, qlx,qly | qlz, p2h, p2l, 0...]
//   B col (point)   k0..15 = [chx,chy,chz, clx,cly,clz, chx,chy | chz, 1, 1, 0...]
//   dot = qh.ch + qh.cl + ql.ch + p2  ~=  -2 c.p + |p|^2   (err ~3e-5)
// Lane maps: A row = l&31, B col = l&31, k-half = l>>5 (8 bf16 each).
// D: col = l&31 (m74/m101-verified); rows = 16 regs x 2 lane-halves,
// bijective over the 32 partials -> min-fold is row-mapping-agnostic.
__global__ __launch_bounds__(1024, 4) void pml_main(
    const float* __restrict__ completed,
    const float* __restrict__ partial,
    float2* __restrict__ slots_out)
{
    const int tid  = threadIdx.x;
    const int lane = tid & 63;
    const int wave = tid >> 6;            // 0..15, owns 128 partials
    const int g    = lane >> 5;           // k-half
    const int lc   = lane & 31;           // A row (partial) / B col (point)
    const int batch = blockIdx.x >> 5;
    const int blkb  = blockIdx.x & (BLKSPB - 1);

    __shared__ uint4 sB[PTILES][2][32];         // 8 KB B-frags (points)
    __shared__ float smin[PTSBLK][WAVES + 1];   // 17 KB, pitch 17
    __shared__ float        rs[4];
    __shared__ unsigned int rc[4];

    const size_t cbase = ((size_t)batch * NCOMP + (size_t)blkb * PTSBLK) * 3;

    // ---- encode B-frags (block's 256 points) into LDS: tid<512 ----
    if (tid < 512) {
        const int tt = tid >> 6;              // tile 0..7
        const int idx = tid & 63;
        const int bg = idx >> 5;              // k-half 0/1
        const int pt = idx & 31;              // point col in tile
        const float* p = completed + cbase + 3 * (tt * 32 + pt);
        float x = p[0], y = p[1], z = p[2];
        uint4 o;
        if (bg == 0) {                        // k0..7
            unsigned int hx = bf16rne(x), hy = bf16rne(y), hz = bf16rne(z);
            unsigned int lx = bf16rne(x - bf16tof(hx));
            unsigned int ly = bf16rne(y - bf16tof(hy));
            unsigned int lz = bf16rne(z - bf16tof(hz));
            o.x = hx | (hy << 16);
            o.y = hz | (lx << 16);
            o.z = ly | (lz << 16);
            o.w = hx | (hy << 16);
        } else {                              // k8..15 = [chz, 1, 1, 0...]
            unsigned int hz = bf16rne(z);
            o.x = hz | (0x3F80u << 16);
            o.y = 0x3F80u;
            o.z = 0u;
            o.w = 0u;
        }
        sB[tt][bg][pt] = o;
    }

    // ---- encode this wave's 4 A-chunks (128 partials) in-register ----
    bf16x8 pa[ACHUNKS];
    {
        const size_t pbase = (size_t)batch * NPART + (size_t)wave * 128;
        #pragma unroll
        for (int i = 0; i < ACHUNKS; ++i) {
            const float* pp = partial + 3 * (pbase + i * 32 + lc);
            float px = pp[0], py = pp[1], pz = pp[2];
            frag_cast fc; fc.u = make_uint4(0u, 0u, 0u, 0u);
            if (g == 0) {                     // k0..7
                float qx = -2.0f * px, qy = -2.0f * py, qz = -2.0f * pz;
                unsigned int qhx = bf16rne(qx), qhy = bf16rne(qy), qhz = bf16rne(qz);
                unsigned int qlx = bf16rne(qx - bf16tof(qhx));
                unsigned int qly = bf16rne(qy - bf16tof(qhy));
                fc.u.x = qhx | (qhy << 16);
                fc.u.y = qhz | (qhx << 16);
                fc.u.z = qhy | (qhz << 16);
                fc.u.w = qlx | (qly << 16);
            } else {                          // k8..15 = [qlz, p2h, p2l, 0...]
                float qz = -2.0f * pz;
                float p2 = fmaf(px, px, fmaf(py, py, pz * pz));
                unsigned int qhz = bf16rne(qz);
                unsigned int qlz = bf16rne(qz - bf16tof(qhz));
                unsigned int p2h = bf16rne(p2);
                unsigned int p2l = bf16rne(p2 - bf16tof(p2h));
                fc.u.x = qlz | (p2h << 16);
                fc.u.y = p2l;
            }
            pa[i] = fc.v;
        }
    }

    __syncthreads();   // sB visible

    const f32x16 zero16 = {0.0f, 0.0f, 0.0f, 0.0f, 0.0f, 0.0f, 0.0f, 0.0f,
                           0.0f, 0.0f, 0.0f, 0.0f, 0.0f, 0.0f, 0.0f, 0.0f};

    // ---- sweep 8 point-tiles: min over partials folds in the accumulator ----
    for (int tile = 0; tile < PTILES; ++tile) {
        frag_cast fc; fc.u = sB[tile][g][lc];
        bf16x8 bf = fc.v;

        f32x16 acc = {FLTMAX, FLTMAX, FLTMAX, FLTMAX, FLTMAX, FLTMAX, FLTMAX, FLTMAX,
                      FLTMAX, FLTMAX, FLTMAX, FLTMAX, FLTMAX, FLTMAX, FLTMAX, FLTMAX};
        #pragma unroll
        for (int i = 0; i < ACHUNKS; ++i) {
            f32x16 d = __builtin_amdgcn_mfma_f32_32x32x16_bf16(pa[i], bf, zero16, 0, 0, 0);
            #pragma unroll
            for (int q = 0; q < 16; ++q)
                acc[q] = fminf(acc[q], d[q]);
        }
        // fold 16 regs (rows within lane-half), then the lane-half fold:
        // rows are bijective over 32 partials -> mapping-agnostic min
        float m0 = fminf(fminf(acc[0],  acc[1]),  fminf(acc[2],  acc[3]));
        float m1 = fminf(fminf(acc[4],  acc[5]),  fminf(acc[6],  acc[7]));
        float m2 = fminf(fminf(acc[8],  acc[9]),  fminf(acc[10], acc[11]));
        float m3 = fminf(fminf(acc[12], acc[13]), fminf(acc[14], acc[15]));
        float m = fminf(fminf(m0, m1), fminf(m2, m3));
        m = fminf(m, __int_as_float(__shfl_xor(__float_as_int(m), 32, 64)));
        if (lane < 32)
            smin[tile * 32 + lc][wave] = m;   // banks (17*(t*32+l))%32: bijective
    }
    __syncthreads();

    // ---- combine 16 wave-minima per point, +c2 (exact f32), mask, reduce ----
    float        v = 0.0f;
    unsigned int c = 0u;
    if (tid < PTSBLK) {
        float t = smin[tid][0];
        #pragma unroll
        for (int g2 = 1; g2 < WAVES; ++g2) t = fminf(t, smin[tid][g2]);
        const float* cp = completed + cbase + 3 * tid;
        float x = cp[0], y = cp[1], z = cp[2];
        float c2 = fmaf(x, x, fmaf(y, y, z * z));
        float m = fmaxf(c2 + t, 0.0f);
        if (m < THRESH) { v = m; c = 1u; }
        #pragma unroll
        for (int off = 32; off >= 1; off >>= 1) {
            v += __shfl_down(v, off, 64);
            c += __shfl_down(c, off, 64);
        }
        if ((tid & 63) == 0) { rs[tid >> 6] = v; rc[tid >> 6] = c; }
    }
    __syncthreads();
    if (tid == 0) {
        float        bs = 0.0f;
        unsigned int bc = 0u;
        #pragma unroll
        for (int w = 0; w < PTSBLK / 64; ++w) { bs += rs[w]; bc += rc[w]; }
        slots_out[blockIdx.x] = make_float2(bs, (float)bc);
    }
}

__global__ __launch_bounds__(256) void pml_fin(
    const float2* __restrict__ slots_in,
    float* __restrict__ out)
{
    const int tid = threadIdx.x;
    float2 sl = slots_in[tid];               // GRID == 256 == blockDim
    float s = sl.x, c = sl.y;
    #pragma unroll
    for (int off = 32; off >= 1; off >>= 1) {
        s += __shfl_down(s, off, 64);
        c += __shfl_down(c, off, 64);
    }
    __shared__ float ss[4], sc[4];
    if ((tid & 63) == 0) { ss[tid >> 6] = s; sc[tid >> 6] = c; }
    __syncthreads();
    if (tid == 0) {
        float s2 = ss[0] + ss[1] + ss[2] + ss[3];
        float c2 = sc[0] + sc[1] + sc[2] + sc[3];
        *out = (c2 > 0.0f) ? (s2 / (c2 + 1e-6f)) : 0.0f;   // WEIGHT = 1.0
    }
}

extern "C" void kernel_launch(void* const* d_in, const int* in_sizes, int n_in,
                              void* d_out, int out_size, void* d_ws, size_t ws_size,
                              hipStream_t stream) {
    const float* completed = (const float*)d_in[0];  // (8, 8192, 3) f32
    const float* partial   = (const float*)d_in[1];  // (8, 2048, 3) f32
    float* out = (float*)d_out;
    float2* slots = (float2*)d_ws;                   // 256 slots, all written
                                                     // before fin reads them:
                                                     // no memset node needed

    pml_main<<<dim3(GRID), dim3(1024), 0, stream>>>(completed, partial, slots);
    pml_fin<<<dim3(1), dim3(256), 0, stream>>>(slots, out);
}